// Round 5
// baseline (259.278 us; speedup 1.0000x reference)
//
#include <hip/hip_runtime.h>
#include <hip/hip_bf16.h>

// MHA: x[2,2048,1024] f32 in, f32 out. 16 heads x 64, causal.
// f32 inputs converted once to bf16 scratch; GEMM/attention use bf16 MFMA
// (16x16x32) with f32 accumulate; projection writes f32.
// Pipeline: convert -> QKV gemm (Q pre-scaled by 0.125*log2e) ->
//           flash attention (S^T trick, exp2, LPT-ordered q-tiles) -> proj.

typedef __hip_bfloat16 bf16;
typedef __attribute__((ext_vector_type(8))) short short8;
typedef __attribute__((ext_vector_type(4))) short short4v;
typedef __attribute__((ext_vector_type(4))) float f32x4;

#define MFMA16(a, b, c) __builtin_amdgcn_mfma_f32_16x16x32_bf16((a), (b), (c), 0, 0, 0)

__device__ __forceinline__ void load_lds16(const void* g, void* l) {
  __builtin_amdgcn_global_load_lds(
      (const __attribute__((address_space(1))) void*)g,
      (__attribute__((address_space(3))) void*)l, 16, 0, 0);
}

// ---------------- f32 -> bf16 conversion pre-pass ----------------------------
__global__ __launch_bounds__(256) void cvt_kernel(
    const float* __restrict__ x, const float* __restrict__ wq,
    const float* __restrict__ wk, const float* __restrict__ wv,
    const float* __restrict__ wo, bf16* __restrict__ xb, bf16* __restrict__ wqb,
    bf16* __restrict__ wkb, bf16* __restrict__ wvb, bf16* __restrict__ wob) {
  const int seg = blockIdx.y;
  const float* src;
  bf16* dst;
  int n;
  if (seg == 0)      { src = x;  dst = xb;  n = 4194304; }
  else if (seg == 1) { src = wq; dst = wqb; n = 1048576; }
  else if (seg == 2) { src = wk; dst = wkb; n = 1048576; }
  else if (seg == 3) { src = wv; dst = wvb; n = 1048576; }
  else               { src = wo; dst = wob; n = 1048576; }
  const int i = (blockIdx.x * 256 + threadIdx.x) * 4;
  if (i >= n) return;
  const float4 v = *(const float4*)(src + i);
  short4v p;
  ((bf16*)&p)[0] = __float2bfloat16(v.x);
  ((bf16*)&p)[1] = __float2bfloat16(v.y);
  ((bf16*)&p)[2] = __float2bfloat16(v.z);
  ((bf16*)&p)[3] = __float2bfloat16(v.w);
  *(short4v*)(dst + i) = p;
}

// ---------------- GEMM: Y[4096,1024] = X @ W^T + bias, optional out scale ----
// BM x 128 tile (BM = 128 or 64), BK=32, 4 waves 2x2, wave (BM/2)x64.
// LDS via global_load_lds w/ source-side XOR swizzle (conflict-free b128 reads).
template <int BM, typename OutT>
__device__ __forceinline__ void gemm_body(const bf16* __restrict__ X,
                                          const bf16* __restrict__ W,
                                          const float* __restrict__ bias,
                                          OutT* __restrict__ Y, float scale) {
  constexpr int K = 1024, N = 1024;
  constexpr int MI = BM / 32;                 // acc tiles per wave in m
  __shared__ bf16 As[BM * 32];
  __shared__ bf16 Bs[128 * 32];
  const int t = threadIdx.x;
  const int lane = t & 63, w = t >> 6;
  const int quad = lane >> 4, r = lane & 15;
  const int m0 = blockIdx.y * BM, n0 = blockIdx.x * 128;
  const int wm = w >> 1, wn = w & 1;

  f32x4 acc[MI][4] = {};

  for (int k0 = 0; k0 < K; k0 += 32) {
    __syncthreads();
#pragma unroll
    for (int p = 0; p < BM / 64; ++p) {       // A chunks: BM*4 16B chunks
      const int c = p * 256 + w * 64 + lane;
      const int row = c >> 2;
      const int scb = (c & 3) ^ ((row >> 1) & 3);
      load_lds16(X + (size_t)(m0 + row) * K + k0 + scb * 8, As + c * 8);
    }
#pragma unroll
    for (int p = 0; p < 2; ++p) {             // B chunks: 512
      const int c = p * 256 + w * 64 + lane;
      const int row = c >> 2;
      const int scb = (c & 3) ^ ((row >> 1) & 3);
      load_lds16(W + (size_t)(n0 + row) * K + k0 + scb * 8, Bs + c * 8);
    }
    __syncthreads();
    short8 af[MI], bfr[4];
#pragma unroll
    for (int i = 0; i < MI; ++i) {
      const int ra = wm * (MI * 16) + i * 16 + r;
      af[i] = *(const short8*)(As + ra * 32 + ((quad ^ ((ra >> 1) & 3)) * 8));
    }
#pragma unroll
    for (int j = 0; j < 4; ++j) {
      const int rb = wn * 64 + j * 16 + r;
      bfr[j] = *(const short8*)(Bs + rb * 32 + ((quad ^ ((rb >> 1) & 3)) * 8));
    }
#pragma unroll
    for (int i = 0; i < MI; ++i)
#pragma unroll
      for (int j = 0; j < 4; ++j)
        acc[i][j] = MFMA16(af[i], bfr[j], acc[i][j]);
  }
#pragma unroll
  for (int i = 0; i < MI; ++i) {
    const int m = m0 + wm * (MI * 16) + i * 16 + quad * 4;
#pragma unroll
    for (int j = 0; j < 4; ++j) {
      const int n = n0 + wn * 64 + j * 16 + r;
      const float bv = bias[n];
#pragma unroll
      for (int g = 0; g < 4; ++g) {
        const float val = (acc[i][j][g] + bv) * scale;
        if constexpr (__is_same(OutT, float))
          Y[(size_t)(m + g) * N + n] = val;
        else
          Y[(size_t)(m + g) * N + n] = __float2bfloat16(val);
      }
    }
  }
}

// Q is pre-scaled by (1/8)*log2(e) so attention can use exp2 directly.
#define QSCALE 0.18033688f

__global__ __launch_bounds__(256) void qkv_kernel(
    const bf16* __restrict__ x, const bf16* __restrict__ Wq,
    const float* __restrict__ bq, const bf16* __restrict__ Wk,
    const float* __restrict__ bk, const bf16* __restrict__ Wv,
    const float* __restrict__ bv, bf16* Qb, bf16* Kb, bf16* Vb) {
  const bf16* W;
  const float* bias;
  bf16* Y;
  float scale = 1.0f;
  if (blockIdx.z == 0) { W = Wq; bias = bq; Y = Qb; scale = QSCALE; }
  else if (blockIdx.z == 1) { W = Wk; bias = bk; Y = Kb; }
  else { W = Wv; bias = bv; Y = Vb; }
  gemm_body<128, bf16>(x, W, bias, Y, scale);
}

__global__ __launch_bounds__(256) void proj_kernel(const bf16* __restrict__ X,
                                                   const bf16* __restrict__ W,
                                                   const float* __restrict__ bias,
                                                   float* __restrict__ Y) {
  gemm_body<64, float>(X, W, bias, Y, 1.0f);  // 64x128 tile -> 512 blocks
}

// ---------------- Flash attention (LPT-ordered) ------------------------------
// One block per 64-row q-tile; j = 31 - blockIdx.x so the longest blocks
// (j=31: 32 k-tiles) dispatch first -> greedy LPT balance at 4 blocks/CU.
// 4 waves; wave w owns q rows w*16..w*16+15. S^T = K*Q^T so softmax reduction
// is in-lane + 2 shuffles; P LDS round-trip is packed b64/b128. Causal mask
// only on the diagonal k-tile. exp2 (scale pre-folded into Q).
__global__ __launch_bounds__(256) void attn_kernel(const bf16* __restrict__ Qb,
                                                   const bf16* __restrict__ Kb,
                                                   const bf16* __restrict__ Vb,
                                                   bf16* __restrict__ Ob) {
  const int j = 31 - blockIdx.x, h = blockIdx.y, b = blockIdx.z;
  const int t = threadIdx.x;
  const int lane = t & 63, w = t >> 6;
  const int quad = lane >> 4, r = lane & 15;

  __shared__ bf16 Ks[64 * 64];
  __shared__ bf16 Vt[64 * 64];      // V transposed: (d, key), XOR-swizzled
  __shared__ bf16 Pl[4][16 * 64];   // per-wave P: (q_local=r, key)

  const int q0 = j * 64;
  const int qrow = q0 + w * 16 + r;

  // Q fragments (B-operand): qf[ks][jj] = Q[qrow][ks*32+quad*8+jj]
  short8 qf[2];
#pragma unroll
  for (int ks = 0; ks < 2; ++ks)
    qf[ks] = *(const short8*)(Qb + (size_t)(b * 2048 + qrow) * 1024 + h * 64 +
                              ks * 32 + quad * 8);

  f32x4 o[4] = {};                  // O^T acc over d (mt)
  float mrow = -1e30f, lrow = 0.f;

  for (int kt = 0; kt <= j; ++kt) {
    const int k0 = kt * 64;
    __syncthreads();
    // stage K tile [64 keys][64 d], source-swizzled
#pragma unroll
    for (int p = 0; p < 2; ++p) {
      const int c = p * 256 + w * 64 + lane;
      const int row = c >> 3;
      const int scb = (c & 7) ^ (row & 7);
      load_lds16(Kb + (size_t)(b * 2048 + k0 + row) * 1024 + h * 64 + scb * 8,
                 Ks + (p * 256 + w * 64) * 8);
    }
    // stage V transposed: lane covers key=lane, wave covers d in [w*16,w*16+16)
    {
      const bf16* vsrc =
          Vb + (size_t)(b * 2048 + k0 + lane) * 1024 + h * 64 + w * 16;
      short8 v0 = *(const short8*)(vsrc);
      short8 v1 = *(const short8*)(vsrc + 8);
      const int s8 = lane >> 3, s7 = lane & 7;
#pragma unroll
      for (int jj = 0; jj < 8; ++jj) {
        const int d0 = w * 16 + jj, d1 = w * 16 + 8 + jj;
        Vt[d0 * 64 + ((s8 ^ jj) * 8) + s7] = ((const bf16*)&v0)[jj];
        Vt[d1 * 64 + ((s8 ^ jj) * 8) + s7] = ((const bf16*)&v1)[jj];
      }
    }
    __syncthreads();

    // S^T = K * Q^T : st[mt], key = k0+mt*16+quad*4+g, q = qrow (col=r)
    f32x4 st[4] = {};
#pragma unroll
    for (int ks = 0; ks < 2; ++ks) {
      short8 kf[4];
#pragma unroll
      for (int mt = 0; mt < 4; ++mt) {
        const int key = mt * 16 + r;
        kf[mt] = *(const short8*)(Ks + key * 64 +
                                  (((ks * 4 + quad) ^ (key & 7)) * 8));
      }
#pragma unroll
      for (int mt = 0; mt < 4; ++mt) st[mt] = MFMA16(kf[mt], qf[ks], st[mt]);
    }

    // causal mask: only the diagonal tile is partial
    if (kt == j) {
#pragma unroll
      for (int mt = 0; mt < 4; ++mt)
#pragma unroll
        for (int g = 0; g < 4; ++g) {
          const int key = k0 + mt * 16 + quad * 4 + g;
          if (key > qrow) st[mt][g] = -1e30f;
        }
    }

    // online softmax (base-2) per q (= lane col r)
    float mx = -1e30f;
#pragma unroll
    for (int mt = 0; mt < 4; ++mt)
#pragma unroll
      for (int g = 0; g < 4; ++g) mx = fmaxf(mx, st[mt][g]);
    mx = fmaxf(mx, __shfl_xor(mx, 16));
    mx = fmaxf(mx, __shfl_xor(mx, 32));
    const float mnew = fmaxf(mrow, mx);
    const float alpha = exp2f(mrow - mnew);
    mrow = mnew;
    float sum = 0.f;
#pragma unroll
    for (int mt = 0; mt < 4; ++mt) {
      bf16 pk[4];
#pragma unroll
      for (int g = 0; g < 4; ++g) {
        const float p = exp2f(st[mt][g] - mnew);
        pk[g] = __float2bfloat16(p);
        sum += __bfloat162float(pk[g]);  // denominator matches bf16 numerator
      }
      // packed write: q=r, keys mt*16+quad*4..+3
      const int key8 = mt * 2 + (quad >> 1);
      const int off = r * 64 + ((key8 ^ (r & 7)) * 8) + (quad & 1) * 4;
      *(short4v*)(&Pl[w][off]) = *(const short4v*)pk;
    }
    sum += __shfl_xor(sum, 16);
    sum += __shfl_xor(sum, 32);
    lrow = lrow * alpha + sum;
#pragma unroll
    for (int mt = 0; mt < 4; ++mt)
#pragma unroll
      for (int g = 0; g < 4; ++g) o[mt][g] *= alpha;

    // wave-local fence: our Pl writes must land before our Pl reads
    asm volatile("s_waitcnt lgkmcnt(0)" ::: "memory");

    // O^T += V^T * P : A = V^T frag (Vt), B = P frag (Pl)
#pragma unroll
    for (int ks = 0; ks < 2; ++ks) {
      short8 vf[4], pf;
#pragma unroll
      for (int mt = 0; mt < 4; ++mt) {
        const int d = mt * 16 + r;
        vf[mt] = *(const short8*)(Vt + d * 64 +
                                  (((ks * 4 + quad) ^ (d & 7)) * 8));
      }
      pf = *(const short8*)(Pl[w] + r * 64 + (((ks * 4 + quad) ^ (r & 7)) * 8));
#pragma unroll
      for (int mt = 0; mt < 4; ++mt) o[mt] = MFMA16(vf[mt], pf, o[mt]);
    }
  }

  // epilogue: O^T[d][q] -> Ob[b, q, h*64+d]; 4 consecutive d -> 8B store
  const float inv = 1.f / lrow;
#pragma unroll
  for (int mt = 0; mt < 4; ++mt) {
    const int d0 = mt * 16 + quad * 4;
    short4v pk;
#pragma unroll
    for (int g = 0; g < 4; ++g)
      ((bf16*)&pk)[g] = __float2bfloat16(o[mt][g] * inv);
    *(short4v*)(Ob + (size_t)(b * 2048 + qrow) * 1024 + h * 64 + d0) = pk;
  }
}

extern "C" void kernel_launch(void* const* d_in, const int* in_sizes, int n_in,
                              void* d_out, int out_size, void* d_ws, size_t ws_size,
                              hipStream_t stream) {
  const float* x  = (const float*)d_in[0];
  const float* Wq = (const float*)d_in[1];
  const float* bq = (const float*)d_in[2];
  const float* Wk = (const float*)d_in[3];
  const float* bk = (const float*)d_in[4];
  const float* Wv = (const float*)d_in[5];
  const float* bv = (const float*)d_in[6];
  const float* Wo = (const float*)d_in[7];
  const float* bo = (const float*)d_in[8];
  float* out = (float*)d_out;

  bf16* xb  = (bf16*)d_ws;                      // 4M
  bf16* wqb = xb  + (size_t)4096 * 1024;        // 1M each
  bf16* wkb = wqb + (size_t)1024 * 1024;
  bf16* wvb = wkb + (size_t)1024 * 1024;
  bf16* wob = wvb + (size_t)1024 * 1024;
  bf16* Qb  = wob + (size_t)1024 * 1024;        // 4M each
  bf16* Kb  = Qb  + (size_t)4096 * 1024;
  bf16* Vb  = Kb  + (size_t)4096 * 1024;
  bf16* Ob  = Vb  + (size_t)4096 * 1024;
  const size_t need = ((size_t)4096 * 1024 * 5 + (size_t)1024 * 1024 * 4) * 2;
  if (ws_size < need) return;

  cvt_kernel<<<dim3(4096, 5), 256, 0, stream>>>(x, Wq, Wk, Wv, Wo,
                                                xb, wqb, wkb, wvb, wob);
  qkv_kernel<<<dim3(8, 32, 3), 256, 0, stream>>>(xb, wqb, bq, wkb, bk, wvb, bv,
                                                 Qb, Kb, Vb);
  attn_kernel<<<dim3(32, 16, 2), 256, 0, stream>>>(Qb, Kb, Vb, Ob);
  proj_kernel<<<dim3(8, 64, 1), 256, 0, stream>>>(Ob, wob, bo, out);
}

// Round 6
// 203.650 us; speedup vs baseline: 1.2732x; 1.2732x over previous
//
#include <hip/hip_runtime.h>
#include <hip/hip_bf16.h>

// MHA: x[2,2048,1024] f32 in, f32 out. 16 heads x 64, causal.
// f32 inputs converted once to bf16 scratch; GEMM/attention use bf16 MFMA
// (16x16x32) with f32 accumulate; projection writes f32.
// Pipeline: convert -> QKV gemm (Q pre-scaled by 0.125*log2e; V written
// TRANSPOSED [1024][4096]) -> flash attention (S^T trick, exp2,
// pair-balanced causal tiles, V^T staged via global_load_lds) -> proj.

typedef __hip_bfloat16 bf16;
typedef __attribute__((ext_vector_type(8))) short short8;
typedef __attribute__((ext_vector_type(4))) short short4v;
typedef __attribute__((ext_vector_type(4))) float f32x4;

#define MFMA16(a, b, c) __builtin_amdgcn_mfma_f32_16x16x32_bf16((a), (b), (c), 0, 0, 0)

__device__ __forceinline__ void load_lds16(const void* g, void* l) {
  __builtin_amdgcn_global_load_lds(
      (const __attribute__((address_space(1))) void*)g,
      (__attribute__((address_space(3))) void*)l, 16, 0, 0);
}

// ---------------- f32 -> bf16 conversion pre-pass ----------------------------
__global__ __launch_bounds__(256) void cvt_kernel(
    const float* __restrict__ x, const float* __restrict__ wq,
    const float* __restrict__ wk, const float* __restrict__ wv,
    const float* __restrict__ wo, bf16* __restrict__ xb, bf16* __restrict__ wqb,
    bf16* __restrict__ wkb, bf16* __restrict__ wvb, bf16* __restrict__ wob) {
  const int seg = blockIdx.y;
  const float* src;
  bf16* dst;
  int n;
  if (seg == 0)      { src = x;  dst = xb;  n = 4194304; }
  else if (seg == 1) { src = wq; dst = wqb; n = 1048576; }
  else if (seg == 2) { src = wk; dst = wkb; n = 1048576; }
  else if (seg == 3) { src = wv; dst = wvb; n = 1048576; }
  else               { src = wo; dst = wob; n = 1048576; }
  const int i = (blockIdx.x * 256 + threadIdx.x) * 4;
  if (i >= n) return;
  const float4 v = *(const float4*)(src + i);
  short4v p;
  ((bf16*)&p)[0] = __float2bfloat16(v.x);
  ((bf16*)&p)[1] = __float2bfloat16(v.y);
  ((bf16*)&p)[2] = __float2bfloat16(v.z);
  ((bf16*)&p)[3] = __float2bfloat16(v.w);
  *(short4v*)(dst + i) = p;
}

// ---------------- GEMM: Y[4096,1024] = X @ W^T + bias ------------------------
// BM x 128 tile, BK=32, 4 waves 2x2. LDS via global_load_lds w/ source-side
// XOR swizzle (conflict-free b128 reads). TRANS: write Y^T [1024][4096]
// (C-layout gives 4 consecutive m per reg quad -> packed 8B stores).
template <int BM, typename OutT, bool TRANS>
__device__ __forceinline__ void gemm_body(const bf16* __restrict__ X,
                                          const bf16* __restrict__ W,
                                          const float* __restrict__ bias,
                                          OutT* __restrict__ Y, float scale) {
  constexpr int K = 1024, N = 1024;
  constexpr int MI = BM / 32;                 // acc tiles per wave in m
  __shared__ bf16 As[BM * 32];
  __shared__ bf16 Bs[128 * 32];
  const int t = threadIdx.x;
  const int lane = t & 63, w = t >> 6;
  const int quad = lane >> 4, r = lane & 15;
  const int m0 = blockIdx.y * BM, n0 = blockIdx.x * 128;
  const int wm = w >> 1, wn = w & 1;

  f32x4 acc[MI][4] = {};

  for (int k0 = 0; k0 < K; k0 += 32) {
    __syncthreads();
#pragma unroll
    for (int p = 0; p < BM / 64; ++p) {       // A chunks
      const int c = p * 256 + w * 64 + lane;
      const int row = c >> 2;
      const int scb = (c & 3) ^ ((row >> 1) & 3);
      load_lds16(X + (size_t)(m0 + row) * K + k0 + scb * 8, As + c * 8);
    }
#pragma unroll
    for (int p = 0; p < 2; ++p) {             // B chunks: 512
      const int c = p * 256 + w * 64 + lane;
      const int row = c >> 2;
      const int scb = (c & 3) ^ ((row >> 1) & 3);
      load_lds16(W + (size_t)(n0 + row) * K + k0 + scb * 8, Bs + c * 8);
    }
    __syncthreads();
    short8 af[MI], bfr[4];
#pragma unroll
    for (int i = 0; i < MI; ++i) {
      const int ra = wm * (MI * 16) + i * 16 + r;
      af[i] = *(const short8*)(As + ra * 32 + ((quad ^ ((ra >> 1) & 3)) * 8));
    }
#pragma unroll
    for (int j = 0; j < 4; ++j) {
      const int rb = wn * 64 + j * 16 + r;
      bfr[j] = *(const short8*)(Bs + rb * 32 + ((quad ^ ((rb >> 1) & 3)) * 8));
    }
#pragma unroll
    for (int i = 0; i < MI; ++i)
#pragma unroll
      for (int j = 0; j < 4; ++j)
        acc[i][j] = MFMA16(af[i], bfr[j], acc[i][j]);
  }
#pragma unroll
  for (int i = 0; i < MI; ++i) {
    const int m = m0 + wm * (MI * 16) + i * 16 + quad * 4;
#pragma unroll
    for (int j = 0; j < 4; ++j) {
      const int n = n0 + wn * 64 + j * 16 + r;
      const float bv = bias[n];
      if constexpr (TRANS) {
        short4v pk;
#pragma unroll
        for (int g = 0; g < 4; ++g)
          ((bf16*)&pk)[g] = __float2bfloat16((acc[i][j][g] + bv) * scale);
        *(short4v*)((bf16*)Y + (size_t)n * 4096 + m) = pk;  // Y^T[n][m..m+3]
      } else {
#pragma unroll
        for (int g = 0; g < 4; ++g) {
          const float val = (acc[i][j][g] + bv) * scale;
          if constexpr (__is_same(OutT, float))
            Y[(size_t)(m + g) * N + n] = val;
          else
            Y[(size_t)(m + g) * N + n] = __float2bfloat16(val);
        }
      }
    }
  }
}

// Q is pre-scaled by (1/8)*log2(e) so attention can use exp2 directly.
#define QSCALE 0.18033688f

__global__ __launch_bounds__(256) void qkv_kernel(
    const bf16* __restrict__ x, const bf16* __restrict__ Wq,
    const float* __restrict__ bq, const bf16* __restrict__ Wk,
    const float* __restrict__ bk, const bf16* __restrict__ Wv,
    const float* __restrict__ bv, bf16* Qb, bf16* Kb, bf16* Vtg) {
  if (blockIdx.z == 0)      gemm_body<128, bf16, false>(x, Wq, bq, Qb, QSCALE);
  else if (blockIdx.z == 1) gemm_body<128, bf16, false>(x, Wk, bk, Kb, 1.0f);
  else                      gemm_body<128, bf16, true >(x, Wv, bv, Vtg, 1.0f);
}

__global__ __launch_bounds__(256) void proj_kernel(const bf16* __restrict__ X,
                                                   const bf16* __restrict__ W,
                                                   const float* __restrict__ bias,
                                                   float* __restrict__ Y) {
  gemm_body<64, float, false>(X, W, bias, Y, 1.0f);  // 64x128 -> 512 blocks
}

// ---------------- Flash attention (pair-balanced) ----------------------------
// 64-row q-tiles, 32 per (b,h). Block handles pair (j, 31-j): exactly 33
// k-tiles -> perfect causal balance (grid == resident capacity, so per-block
// balance is what matters — round-5 LPT experiment showed dispatch-order
// balancing is dead when all blocks are co-resident). 4 waves; wave w owns
// q rows w*16..w*16+15. S^T = K*Q^T. V^T comes pre-transposed from the QKV
// GEMM and is staged with global_load_lds like K (no in-kernel transpose).
__global__ __launch_bounds__(256) void attn_kernel(const bf16* __restrict__ Qb,
                                                   const bf16* __restrict__ Kb,
                                                   const bf16* __restrict__ Vtg,
                                                   bf16* __restrict__ Ob) {
  const int pair = blockIdx.x, h = blockIdx.y, b = blockIdx.z;
  const int t = threadIdx.x;
  const int lane = t & 63, w = t >> 6;
  const int quad = lane >> 4, r = lane & 15;

  __shared__ bf16 Ks[64 * 64];
  __shared__ bf16 Vt[64 * 64];      // V^T tile: (d, key), XOR-swizzled
  __shared__ bf16 Pl[4][16 * 64];   // per-wave P: (q_local=r, key)

#pragma unroll 1
  for (int sel = 0; sel < 2; ++sel) {
    const int j = sel ? (31 - pair) : pair;   // q-tile index 0..31
    const int q0 = j * 64;
    const int qrow = q0 + w * 16 + r;

    // Q fragments (B-operand): qf[ks][jj] = Q[qrow][ks*32+quad*8+jj]
    short8 qf[2];
#pragma unroll
    for (int ks = 0; ks < 2; ++ks)
      qf[ks] = *(const short8*)(Qb + (size_t)(b * 2048 + qrow) * 1024 + h * 64 +
                                ks * 32 + quad * 8);

    f32x4 o[4] = {};                // O^T acc over d (mt)
    float mrow = -1e30f, lrow = 0.f;

    for (int kt = 0; kt <= j; ++kt) {
      const int k0 = kt * 64;
      __syncthreads();
      // stage K tile [64 keys][64 d], source-swizzled
#pragma unroll
      for (int p = 0; p < 2; ++p) {
        const int c = p * 256 + w * 64 + lane;
        const int row = c >> 3;
        const int scb = (c & 7) ^ (row & 7);
        load_lds16(Kb + (size_t)(b * 2048 + k0 + row) * 1024 + h * 64 + scb * 8,
                   Ks + c * 8);
      }
      // stage V^T tile [64 d][64 keys] from pre-transposed global
#pragma unroll
      for (int p = 0; p < 2; ++p) {
        const int c = p * 256 + w * 64 + lane;
        const int row = c >> 3;                 // d 0..63
        const int scb = (c & 7) ^ (row & 7);
        load_lds16(Vtg + (size_t)(h * 64 + row) * 4096 + b * 2048 + k0 + scb * 8,
                   Vt + c * 8);
      }
      __syncthreads();

      // S^T = K * Q^T : st[mt], key = k0+mt*16+quad*4+g, q = qrow (col=r)
      f32x4 st[4] = {};
#pragma unroll
      for (int ks = 0; ks < 2; ++ks) {
        short8 kf[4];
#pragma unroll
        for (int mt = 0; mt < 4; ++mt) {
          const int key = mt * 16 + r;
          kf[mt] = *(const short8*)(Ks + key * 64 +
                                    (((ks * 4 + quad) ^ (key & 7)) * 8));
        }
#pragma unroll
        for (int mt = 0; mt < 4; ++mt) st[mt] = MFMA16(kf[mt], qf[ks], st[mt]);
      }

      // causal mask: only the diagonal tile is partial
      if (kt == j) {
#pragma unroll
        for (int mt = 0; mt < 4; ++mt)
#pragma unroll
          for (int g = 0; g < 4; ++g) {
            const int key = k0 + mt * 16 + quad * 4 + g;
            if (key > qrow) st[mt][g] = -1e30f;
          }
      }

      // online softmax (base-2) per q (= lane col r)
      float mx = -1e30f;
#pragma unroll
      for (int mt = 0; mt < 4; ++mt)
#pragma unroll
        for (int g = 0; g < 4; ++g) mx = fmaxf(mx, st[mt][g]);
      mx = fmaxf(mx, __shfl_xor(mx, 16));
      mx = fmaxf(mx, __shfl_xor(mx, 32));
      const float mnew = fmaxf(mrow, mx);
      const float alpha = exp2f(mrow - mnew);
      mrow = mnew;
      float sum = 0.f;
#pragma unroll
      for (int mt = 0; mt < 4; ++mt) {
        bf16 pk[4];
#pragma unroll
        for (int g = 0; g < 4; ++g) {
          const float p = exp2f(st[mt][g] - mnew);
          pk[g] = __float2bfloat16(p);
          sum += __bfloat162float(pk[g]);  // denominator matches bf16 numerator
        }
        // packed write: q=r, keys mt*16+quad*4..+3
        const int key8 = mt * 2 + (quad >> 1);
        const int off = r * 64 + ((key8 ^ (r & 7)) * 8) + (quad & 1) * 4;
        *(short4v*)(&Pl[w][off]) = *(const short4v*)pk;
      }
      sum += __shfl_xor(sum, 16);
      sum += __shfl_xor(sum, 32);
      lrow = lrow * alpha + sum;
#pragma unroll
      for (int mt = 0; mt < 4; ++mt)
#pragma unroll
        for (int g = 0; g < 4; ++g) o[mt][g] *= alpha;

      // wave-local fence: our Pl writes must land before our Pl reads
      asm volatile("s_waitcnt lgkmcnt(0)" ::: "memory");

      // O^T += V^T * P : A = V^T frag (Vt), B = P frag (Pl)
#pragma unroll
      for (int ks = 0; ks < 2; ++ks) {
        short8 vf[4], pf;
#pragma unroll
        for (int mt = 0; mt < 4; ++mt) {
          const int d = mt * 16 + r;
          vf[mt] = *(const short8*)(Vt + d * 64 +
                                    (((ks * 4 + quad) ^ (d & 7)) * 8));
        }
        pf = *(const short8*)(Pl[w] + r * 64 + (((ks * 4 + quad) ^ (r & 7)) * 8));
#pragma unroll
        for (int mt = 0; mt < 4; ++mt) o[mt] = MFMA16(vf[mt], pf, o[mt]);
      }
    }

    // epilogue: O^T[d][q] -> Ob[b, q, h*64+d]; 4 consecutive d -> 8B store
    const float inv = 1.f / lrow;
#pragma unroll
    for (int mt = 0; mt < 4; ++mt) {
      const int d0 = mt * 16 + quad * 4;
      short4v pk;
#pragma unroll
      for (int g = 0; g < 4; ++g)
        ((bf16*)&pk)[g] = __float2bfloat16(o[mt][g] * inv);
      *(short4v*)(Ob + (size_t)(b * 2048 + qrow) * 1024 + h * 64 + d0) = pk;
    }
  }
}

extern "C" void kernel_launch(void* const* d_in, const int* in_sizes, int n_in,
                              void* d_out, int out_size, void* d_ws, size_t ws_size,
                              hipStream_t stream) {
  const float* x  = (const float*)d_in[0];
  const float* Wq = (const float*)d_in[1];
  const float* bq = (const float*)d_in[2];
  const float* Wk = (const float*)d_in[3];
  const float* bk = (const float*)d_in[4];
  const float* Wv = (const float*)d_in[5];
  const float* bv = (const float*)d_in[6];
  const float* Wo = (const float*)d_in[7];
  const float* bo = (const float*)d_in[8];
  float* out = (float*)d_out;

  bf16* xb  = (bf16*)d_ws;                      // 4M
  bf16* wqb = xb  + (size_t)4096 * 1024;        // 1M each
  bf16* wkb = wqb + (size_t)1024 * 1024;
  bf16* wvb = wkb + (size_t)1024 * 1024;
  bf16* wob = wvb + (size_t)1024 * 1024;
  bf16* Qb  = wob + (size_t)1024 * 1024;        // 4M each
  bf16* Kb  = Qb  + (size_t)4096 * 1024;
  bf16* Vtg = Kb  + (size_t)4096 * 1024;        // V^T [1024][4096]
  bf16* Ob  = Vtg + (size_t)4096 * 1024;
  const size_t need = ((size_t)4096 * 1024 * 5 + (size_t)1024 * 1024 * 4) * 2;
  if (ws_size < need) return;

  cvt_kernel<<<dim3(4096, 5), 256, 0, stream>>>(x, Wq, Wk, Wv, Wo,
                                                xb, wqb, wkb, wvb, wob);
  qkv_kernel<<<dim3(8, 32, 3), 256, 0, stream>>>(xb, wqb, bq, wkb, bk, wvb, bv,
                                                 Qb, Kb, Vtg);
  attn_kernel<<<dim3(16, 16, 2), 256, 0, stream>>>(Qb, Kb, Vtg, Ob);
  proj_kernel<<<dim3(8, 64, 1), 256, 0, stream>>>(Ob, wob, bo, out);
}